// Round 8
// baseline (39.167 us; speedup 1.0000x reference)
//
#include <hip/hip_runtime.h>
#include <hip/hip_fp16.h>

// Correlation layer, specialized: s1=2, s2=1, d=4 -> integer even sampling,
// bilinear weights exactly 0 -> pure gather:
// out[b, j*9+i, h1, w1] = (1/256) * sum_c x1[b,c,2h1,2w1] * x2[b,c,2(h1+j-4),2(w1+i-4)]
//
// MFMA formulation: per (b,h1,j): D[w1, x] = sum_c A[c,w1] * B[c, h1+j-4, x]
// banded 12x20 GEMM via 16x16x32 bf16 MFMA; K=64 per block (cz in 0..3),
// fp16 partials + coalesced reduce.

typedef __attribute__((ext_vector_type(8))) short short8;
typedef __attribute__((ext_vector_type(4))) float f32x4;

constexpr int NB = 16, NC = 256, NH = 48, NW = 48;
constexpr int H1 = 24, W1 = 24, NK = 81, HW = NH * NW;
constexpr int CZ = 4, CPB = 64;          // 4 K-splits x 64 channels
constexpr int TH = 4;                    // h1 rows per block
constexpr int NTILE = 12 * 16;           // (h1t*2+wh)*16 + b = 192 tiles
constexpr int PPT = 9 * 4 * 9 * 12;      // 3888 halfs per (cz,tile)
constexpr int OUTSZ = NB * NK * H1 * W1; // 746496

__device__ __forceinline__ unsigned f2bf(float x) {
  unsigned u = __float_as_uint(x);
  return (u + 0x7FFFu + ((u >> 16) & 1u)) >> 16;   // RNE to bf16 (top 16 bits)
}

__global__ __launch_bounds__(384) void corr_mfma(
    const float* __restrict__ x1, const float* __restrict__ x2,
    __half* __restrict__ part)
{
  const int t  = threadIdx.x;
  const int bx = blockIdx.x;            // 0..11 = h1t*2 + wh
  const int b  = blockIdx.y;            // 0..15
  const int cz = blockIdx.z;            // 0..3
  const int h1t = bx >> 1, wh = bx & 1;
  const int h1base = h1t * TH;
  const int wbase  = wh * 12;
  const int cb = cz * CPB;

  // [r][xloc][c] bf16 (xloc 0..19 data; 20..23 junk -> lands at i>=9, never stored)
  __shared__ __align__(16) unsigned short Blds[12][24][64];   // 36 KB
  __shared__ __align__(16) unsigned short Albs[4][16][64];    // 8 KB (w1loc 12..15 junk)

  // ---- stage B: items (cp 32, r 12, xp 10) = 3840 = 384 x 10, 2 channels/item ----
  const float* p2 = x2 + (size_t)(b * NC + cb) * HW;
  #pragma unroll
  for (int q = 0; q < 10; ++q) {
    const int idx = q * 384 + t;
    const int xp = idx % 10;
    const int r  = (idx / 10) % 12;
    const int cp = idx / 120;
    const int c  = 2 * cp;
    const int ys = h1base - 4 + r;
    const int col = 4 * xp - 8 + 2 * wbase;    // orig col of float4 (covers 2 even cols)
    float4 L0 = make_float4(0.f,0.f,0.f,0.f), L1 = make_float4(0.f,0.f,0.f,0.f);
    if (ys >= 0 && ys < H1 && col >= 0 && col <= 44) {
      const float* pp = p2 + (size_t)c * HW + (size_t)(2 * ys) * NW + col;
      L0 = *(const float4*)pp;
      L1 = *(const float4*)(pp + HW);
    }
    *(unsigned*)&Blds[r][2 * xp][c]     = f2bf(L0.x) | (f2bf(L1.x) << 16);
    *(unsigned*)&Blds[r][2 * xp + 1][c] = f2bf(L0.z) | (f2bf(L1.z) << 16);
  }
  // ---- stage A: items (cp 32, h 4, wp 6) = 768 = 384 x 2 ----
  const float* p1 = x1 + (size_t)(b * NC + cb) * HW;
  #pragma unroll
  for (int q = 0; q < 2; ++q) {
    const int idx = q * 384 + t;
    const int wp = idx % 6;
    const int h  = (idx / 6) % 4;
    const int cp = idx / 24;
    const int c  = 2 * cp;
    const float* pp = p1 + (size_t)c * HW + (size_t)(2 * (h1base + h)) * NW
                    + (2 * wbase + 4 * wp);
    const float4 L0 = *(const float4*)pp;
    const float4 L1 = *(const float4*)(pp + HW);
    *(unsigned*)&Albs[h][2 * wp][c]     = f2bf(L0.x) | (f2bf(L1.x) << 16);
    *(unsigned*)&Albs[h][2 * wp + 1][c] = f2bf(L0.z) | (f2bf(L1.z) << 16);
  }
  __syncthreads();

  // ---- compute: wave-unit = (j, h1l); 36 units over 6 waves, 6 each ----
  const int wave = t >> 6, lane = t & 63;
  const int ln15 = lane & 15, lh = lane >> 4;
  const int tileid = bx * 16 + b;
  __half* pbase = part + ((size_t)cz * NTILE + tileid) * PPT;

  #pragma unroll
  for (int u6 = 0; u6 < 6; ++u6) {
    const int unit = u6 * 6 + wave;     // 0..35
    const int j = unit >> 2, h1l = unit & 3;
    const int r = h1l + j;              // 0..11
    // A-frag: m = lane&15 (w1loc), k = (lane>>4)*8+i ; ks halves of K=64
    const short8 a0 = *(const short8*)&Albs[h1l][ln15][lh * 8];
    const short8 a1 = *(const short8*)&Albs[h1l][ln15][32 + lh * 8];
    // B-frag: n = lane&15 (xloc), same k mapping
    const short8 b00 = *(const short8*)&Blds[r][ln15][lh * 8];
    const short8 b01 = *(const short8*)&Blds[r][ln15][32 + lh * 8];
    const short8 b10 = *(const short8*)&Blds[r][16 + ln15][lh * 8];
    const short8 b11 = *(const short8*)&Blds[r][16 + ln15][32 + lh * 8];
    f32x4 acc0 = {0.f, 0.f, 0.f, 0.f}, acc1 = {0.f, 0.f, 0.f, 0.f};
    acc0 = __builtin_amdgcn_mfma_f32_16x16x32_bf16(a0, b00, acc0, 0, 0, 0);
    acc0 = __builtin_amdgcn_mfma_f32_16x16x32_bf16(a1, b01, acc0, 0, 0, 0);
    acc1 = __builtin_amdgcn_mfma_f32_16x16x32_bf16(a0, b10, acc1, 0, 0, 0);
    acc1 = __builtin_amdgcn_mfma_f32_16x16x32_bf16(a1, b11, acc1, 0, 0, 0);
    // D layout: row(w1loc) = (lane>>4)*4 + q, col(xloc) = lane&15
    __half* pj = pbase + ((size_t)j * 4 + h1l) * 108;   // [i][w1loc] 9x12 halfs
    #pragma unroll
    for (int q = 0; q < 4; ++q) {
      const int w1loc = lh * 4 + q;
      if (w1loc < 12) {
        const int i0 = ln15 - w1loc;            // Nt0: xloc = ln15
        if (i0 >= 0 && i0 <= 8) pj[i0 * 12 + w1loc] = __float2half(acc0[q]);
        const int i1 = 16 + ln15 - w1loc;       // Nt1 (>=5 always)
        if (i1 <= 8) pj[i1 * 12 + w1loc] = __float2half(acc1[q]);
      }
    }
  }
}

// Reduce: thread -> one output float4; sums 4 cz slices, scales 1/256.
__global__ __launch_bounds__(256) void corr_reduce(const __half* __restrict__ part,
                                                   float* __restrict__ out)
{
  const int n = blockIdx.x * 256 + threadIdx.x;   // 0..186623
  if (n >= OUTSZ / 4) return;
  const int w1q = n % 6;
  const int h1  = (n / 6) % 24;
  const int k   = (n / 144) % 81;
  const int b   = n / 11664;
  const int j = k / 9, i = k % 9;
  const int h1t = h1 >> 2, h1l = h1 & 3;
  const int wh = w1q / 3, wl0 = (w1q % 3) * 4;
  const int tileid = (h1t * 2 + wh) * 16 + b;
  const size_t off = (((size_t)tileid * 9 + j) * 4 + h1l) * 108 + i * 12 + wl0;
  float s0 = 0.f, s1 = 0.f, s2 = 0.f, s3 = 0.f;
  #pragma unroll
  for (int cz = 0; cz < CZ; ++cz) {
    const __half* p = part + (size_t)cz * NTILE * PPT + off;
    s0 += __half2float(p[0]); s1 += __half2float(p[1]);
    s2 += __half2float(p[2]); s3 += __half2float(p[3]);
  }
  const float sc = 1.f / 256.f;
  *(float4*)&out[(size_t)n * 4] = make_float4(s0 * sc, s1 * sc, s2 * sc, s3 * sc);
}

// ---- fallback (ws too small): round-6 vector kernel, atomicAdd into out ----
__global__ __launch_bounds__(256, 4) void corr_atomic(
    const float* __restrict__ x1, const float* __restrict__ x2,
    float* __restrict__ out)
{
  const int t   = threadIdx.x;
  const int h1t = blockIdx.x;
  const int b   = blockIdx.y;
  const int cz  = blockIdx.z;     // 0..7, 32 ch each
  const int h1base = h1t * TH;
  __shared__ float s1m[16][TH][24];
  __shared__ float s2m[16][12][36];
  const int h1l = t / 54, rr = t % 54, j = rr / 6, wg = rr % 6;
  const float* base1 = x1 + (size_t)(b * NC + cz * 32) * HW;
  const float* base2 = x2 + (size_t)(b * NC + cz * 32) * HW;
  float acc[9][4];
  #pragma unroll
  for (int i = 0; i < 9; ++i) { acc[i][0]=0.f; acc[i][1]=0.f; acc[i][2]=0.f; acc[i][3]=0.f; }
  for (int ch = 0; ch < 2; ++ch) {
    if (ch) __syncthreads();
    const float* p2 = base2 + (size_t)ch * 16 * HW;
    #pragma unroll
    for (int q = 0; q < 12; ++q) {
      const int idx = t + q * 256;
      const int xh = idx & 15, r = (idx >> 4) % 12, c = idx / 192;
      const int ys = h1base - 4 + r;
      float vx = 0.f, vz = 0.f;
      if (ys >= 0 && ys < H1 && xh >= 2 && xh <= 13) {
        const float4 v = *(const float4*)&p2[(size_t)c * HW + (size_t)(2 * ys) * NW + (4 * xh - 8)];
        vx = v.x; vz = v.z;
      }
      s2m[c][r][2 * xh] = vx; s2m[c][r][2 * xh + 1] = vz;
    }
    const float* p1 = base1 + (size_t)ch * 16 * HW;
    #pragma unroll
    for (int q = 0; q < 3; ++q) {
      const int idx = t + q * 256;
      const int xq = idx % 12, hh = (idx / 12) & 3, c = idx / 48;
      const float4 v = *(const float4*)&p1[(size_t)c * HW + (size_t)(2 * (h1base + hh)) * NW + 4 * xq];
      s1m[c][hh][2 * xq] = v.x; s1m[c][hh][2 * xq + 1] = v.z;
    }
    __syncthreads();
    if (t < 216) {
      #pragma unroll 4
      for (int c = 0; c < 16; ++c) {
        const float4 a4 = *(const float4*)&s1m[c][h1l][wg * 4];
        const float* xr = &s2m[c][h1l + j][wg * 4];
        const float4 b0 = *(const float4*)&xr[0];
        const float4 b1 = *(const float4*)&xr[4];
        const float4 b2 = *(const float4*)&xr[8];
        const float av[4]  = {a4.x, a4.y, a4.z, a4.w};
        const float xw[12] = {b0.x,b0.y,b0.z,b0.w,b1.x,b1.y,b1.z,b1.w,b2.x,b2.y,b2.z,b2.w};
        #pragma unroll
        for (int i = 0; i < 9; ++i)
          #pragma unroll
          for (int w = 0; w < 4; ++w)
            acc[i][w] = fmaf(av[w], xw[w + i], acc[i][w]);
      }
    }
  }
  if (t >= 216) return;
  const int h1 = h1base + h1l, w1 = wg * 4;
  #pragma unroll
  for (int i = 0; i < 9; ++i) {
    const int k = j * 9 + i;
    #pragma unroll
    for (int w = 0; w < 4; ++w)
      atomicAdd(&out[((size_t)(b * NK + k) * H1 + h1) * W1 + w1 + w],
                acc[i][w] * (1.f / 256.f));
  }
}

extern "C" void kernel_launch(void* const* d_in, const int* in_sizes, int n_in,
                              void* d_out, int out_size, void* d_ws, size_t ws_size,
                              hipStream_t stream) {
  const float* x1 = (const float*)d_in[0];
  const float* x2 = (const float*)d_in[1];
  float* out = (float*)d_out;

  const size_t need = (size_t)CZ * NTILE * PPT * sizeof(__half);  // ~5.97 MB
  if (ws_size >= need) {
    __half* part = (__half*)d_ws;
    corr_mfma<<<dim3(12, 16, CZ), 384, 0, stream>>>(x1, x2, part);
    corr_reduce<<<(OUTSZ / 4 + 255) / 256, 256, 0, stream>>>(part, out);
  } else {
    hipMemsetAsync(d_out, 0, (size_t)OUTSZ * sizeof(float), stream);
    corr_atomic<<<dim3(6, 16, 8), 256, 0, stream>>>(x1, x2, out);
  }
}

// Round 9
// 37.777 us; speedup vs baseline: 1.0368x; 1.0368x over previous
//
#include <hip/hip_runtime.h>
#include <hip/hip_fp16.h>

// Correlation layer, specialized: s1=2, s2=1, d=4 -> integer even sampling,
// bilinear weights exactly 0 -> pure gather:
// out[b, j*9+i, h1, w1] = (1/256) * sum_c x1[b,c,2h1,2w1] * x2[b,c,2(h1+j-4),2(w1+i-4)]
//
// MFMA formulation: per (b,h1,j): D[w1, x] = sum_c A[c,w1] * B[c, h1+j-4, x]
// 16x16x32 bf16 MFMA, K=64 per block (cz in 0..3), T2 XOR-swizzled LDS operands,
// band epilogue staged through LDS -> coalesced fp16 partial write + reduce.

typedef __attribute__((ext_vector_type(8))) short short8;
typedef __attribute__((ext_vector_type(4))) float f32x4;

constexpr int NB = 16, NC = 256, NH = 48, NW = 48;
constexpr int H1 = 24, W1 = 24, NK = 81, HW = NH * NW;
constexpr int CZ = 4, CPB = 64;          // 4 K-splits x 64 channels
constexpr int TH = 4;                    // h1 rows per block
constexpr int NTILE = 12 * 16;           // (h1t*2+wh)*16 + b
constexpr int PPT = 9 * 4 * 9 * 12;      // 3888 halfs per (cz,tile)
constexpr int OUTSZ = NB * NK * H1 * W1; // 746496

__device__ __forceinline__ unsigned f2bf(float x) {
  unsigned u = __float_as_uint(x);
  return (u + 0x7FFFu + ((u >> 16) & 1u)) >> 16;   // RNE to bf16
}
__device__ __forceinline__ int swz(int row, int k) {  // T2: 16B-granular XOR swizzle
  return k ^ ((row & 7) << 3);                        // half-index domain
}

__global__ __launch_bounds__(384) void corr_mfma(
    const float* __restrict__ x1, const float* __restrict__ x2,
    __half* __restrict__ part)
{
  const int t  = threadIdx.x;
  const int bx = blockIdx.x;            // 0..11 = h1t*2 + wh
  const int b  = blockIdx.y;            // 0..15
  const int cz = blockIdx.z;            // 0..3
  const int h1t = bx >> 1, wh = bx & 1;
  const int h1base = h1t * TH;
  const int wbase  = wh * 12;
  const int cb = cz * CPB;

  // [r][xloc][c] bf16, k-swizzled by xloc (row stride 128B -> T2 required)
  __shared__ __align__(16) unsigned short Blds[12][24][64];   // 36 KB
  __shared__ __align__(16) unsigned short Albs[4][16][64];    // 8 KB
  __shared__ __align__(16) __half bandLds[PPT];               // 7.8 KB

  // ---- stage B: items (cp 32, r 12, xp 10) = 3840 = 384 x 10 ----
  const float* p2 = x2 + (size_t)(b * NC + cb) * HW;
  #pragma unroll
  for (int q = 0; q < 10; ++q) {
    const int idx = q * 384 + t;
    const int xp = idx % 10;
    const int r  = (idx / 10) % 12;
    const int cp = idx / 120;
    const int c  = 2 * cp;
    const int ys = h1base - 4 + r;
    const int col = 4 * xp - 8 + 2 * wbase;
    float4 L0 = make_float4(0.f,0.f,0.f,0.f), L1 = make_float4(0.f,0.f,0.f,0.f);
    if (ys >= 0 && ys < H1 && col >= 0 && col <= 44) {
      const float* pp = p2 + (size_t)c * HW + (size_t)(2 * ys) * NW + col;
      L0 = *(const float4*)pp;
      L1 = *(const float4*)(pp + HW);
    }
    const int x0 = 2 * xp, x1c = 2 * xp + 1;
    *(unsigned*)&Blds[r][x0][swz(x0, c)]   = f2bf(L0.x) | (f2bf(L1.x) << 16);
    *(unsigned*)&Blds[r][x1c][swz(x1c, c)] = f2bf(L0.z) | (f2bf(L1.z) << 16);
  }
  // ---- stage A: items (cp 32, h 4, wp 6) = 768 = 384 x 2 ----
  const float* p1 = x1 + (size_t)(b * NC + cb) * HW;
  #pragma unroll
  for (int q = 0; q < 2; ++q) {
    const int idx = q * 384 + t;
    const int wp = idx % 6;
    const int h  = (idx / 6) % 4;
    const int cp = idx / 24;
    const int c  = 2 * cp;
    const float* pp = p1 + (size_t)c * HW + (size_t)(2 * (h1base + h)) * NW
                    + (2 * wbase + 4 * wp);
    const float4 L0 = *(const float4*)pp;
    const float4 L1 = *(const float4*)(pp + HW);
    const int w0 = 2 * wp, w1c = 2 * wp + 1;
    *(unsigned*)&Albs[h][w0][swz(w0, c)]   = f2bf(L0.x) | (f2bf(L1.x) << 16);
    *(unsigned*)&Albs[h][w1c][swz(w1c, c)] = f2bf(L0.z) | (f2bf(L1.z) << 16);
  }
  __syncthreads();

  // ---- compute: wave-unit = (j, h1l); 36 units over 6 waves ----
  const int wave = t >> 6, lane = t & 63;
  const int ln15 = lane & 15, lh = lane >> 4;
  const int kA = swz(ln15, lh * 8), kB = swz(ln15, 32 + lh * 8);

  #pragma unroll
  for (int u6 = 0; u6 < 6; ++u6) {
    const int unit = u6 * 6 + wave;     // 0..35
    const int j = unit >> 2, h1l = unit & 3;
    const int r = h1l + j;              // 0..11
    const short8 a0 = *(const short8*)&Albs[h1l][ln15][kA];
    const short8 a1 = *(const short8*)&Albs[h1l][ln15][kB];
    const short8 b00 = *(const short8*)&Blds[r][ln15][kA];
    const short8 b01 = *(const short8*)&Blds[r][ln15][kB];
    const short8 b10 = *(const short8*)&Blds[r][16 + ln15][kA];
    const short8 b11 = *(const short8*)&Blds[r][16 + ln15][kB];
    f32x4 acc0 = {0.f, 0.f, 0.f, 0.f}, acc1 = {0.f, 0.f, 0.f, 0.f};
    acc0 = __builtin_amdgcn_mfma_f32_16x16x32_bf16(a0, b00, acc0, 0, 0, 0);
    acc0 = __builtin_amdgcn_mfma_f32_16x16x32_bf16(a1, b01, acc0, 0, 0, 0);
    acc1 = __builtin_amdgcn_mfma_f32_16x16x32_bf16(a0, b10, acc1, 0, 0, 0);
    acc1 = __builtin_amdgcn_mfma_f32_16x16x32_bf16(a1, b11, acc1, 0, 0, 0);
    // D layout: row(w1loc) = (lane>>4)*4 + q, col(xloc) = lane&15
    __half* pj = bandLds + ((size_t)j * 4 + h1l) * 108;   // [i][w1loc] 9x12
    #pragma unroll
    for (int q = 0; q < 4; ++q) {
      const int w1loc = lh * 4 + q;
      if (w1loc < 12) {
        const int i0 = ln15 - w1loc;            // Nt0: xloc = ln15
        if (i0 >= 0 && i0 <= 8) pj[i0 * 12 + w1loc] = __float2half(acc0[q]);
        const int i1 = 16 + ln15 - w1loc;       // Nt1: xloc = 16+ln15
        if (i1 <= 8) pj[i1 * 12 + w1loc] = __float2half(acc1[q]);
      }
    }
  }
  __syncthreads();

  // ---- stream band block to global: 3888 halfs = 486 float4, coalesced ----
  const int tileid = bx * 16 + b;
  float4* dst4 = (float4*)(part + ((size_t)cz * NTILE + tileid) * PPT);
  const float4* src4 = (const float4*)bandLds;
  #pragma unroll 2
  for (int idx = t; idx < PPT / 8; idx += 384)
    dst4[idx] = src4[idx];
}

// Reduce: thread -> one output float4; sums 4 cz slices, scales 1/256.
__global__ __launch_bounds__(256) void corr_reduce(const __half* __restrict__ part,
                                                   float* __restrict__ out)
{
  const int n = blockIdx.x * 256 + threadIdx.x;   // 0..186623
  if (n >= OUTSZ / 4) return;
  const int w1q = n % 6;
  const int h1  = (n / 6) % 24;
  const int k   = (n / 144) % 81;
  const int b   = n / 11664;
  const int j = k / 9, i = k % 9;
  const int h1t = h1 >> 2, h1l = h1 & 3;
  const int wh = w1q / 3, wl0 = (w1q % 3) * 4;
  const int tileid = (h1t * 2 + wh) * 16 + b;
  const size_t off = (((size_t)tileid * 9 + j) * 4 + h1l) * 108 + i * 12 + wl0;
  float s0 = 0.f, s1 = 0.f, s2 = 0.f, s3 = 0.f;
  #pragma unroll
  for (int cz = 0; cz < CZ; ++cz) {
    const __half* p = part + (size_t)cz * NTILE * PPT + off;
    s0 += __half2float(p[0]); s1 += __half2float(p[1]);
    s2 += __half2float(p[2]); s3 += __half2float(p[3]);
  }
  const float sc = 1.f / 256.f;
  *(float4*)&out[(size_t)n * 4] = make_float4(s0 * sc, s1 * sc, s2 * sc, s3 * sc);
}

// ---- fallback (ws too small): vector kernel, atomicAdd into out ----
__global__ __launch_bounds__(256, 4) void corr_atomic(
    const float* __restrict__ x1, const float* __restrict__ x2,
    float* __restrict__ out)
{
  const int t   = threadIdx.x;
  const int h1t = blockIdx.x;
  const int b   = blockIdx.y;
  const int cz  = blockIdx.z;     // 0..7, 32 ch each
  const int h1base = h1t * TH;
  __shared__ float s1m[16][TH][24];
  __shared__ float s2m[16][12][36];
  const int h1l = t / 54, rr = t % 54, j = rr / 6, wg = rr % 6;
  const float* base1 = x1 + (size_t)(b * NC + cz * 32) * HW;
  const float* base2 = x2 + (size_t)(b * NC + cz * 32) * HW;
  float acc[9][4];
  #pragma unroll
  for (int i = 0; i < 9; ++i) { acc[i][0]=0.f; acc[i][1]=0.f; acc[i][2]=0.f; acc[i][3]=0.f; }
  for (int ch = 0; ch < 2; ++ch) {
    if (ch) __syncthreads();
    const float* p2 = base2 + (size_t)ch * 16 * HW;
    #pragma unroll
    for (int q = 0; q < 12; ++q) {
      const int idx = t + q * 256;
      const int xh = idx & 15, r = (idx >> 4) % 12, c = idx / 192;
      const int ys = h1base - 4 + r;
      float vx = 0.f, vz = 0.f;
      if (ys >= 0 && ys < H1 && xh >= 2 && xh <= 13) {
        const float4 v = *(const float4*)&p2[(size_t)c * HW + (size_t)(2 * ys) * NW + (4 * xh - 8)];
        vx = v.x; vz = v.z;
      }
      s2m[c][r][2 * xh] = vx; s2m[c][r][2 * xh + 1] = vz;
    }
    const float* p1 = base1 + (size_t)ch * 16 * HW;
    #pragma unroll
    for (int q = 0; q < 3; ++q) {
      const int idx = t + q * 256;
      const int xq = idx % 12, hh = (idx / 12) & 3, c = idx / 48;
      const float4 v = *(const float4*)&p1[(size_t)c * HW + (size_t)(2 * (h1base + hh)) * NW + 4 * xq];
      s1m[c][hh][2 * xq] = v.x; s1m[c][hh][2 * xq + 1] = v.z;
    }
    __syncthreads();
    if (t < 216) {
      #pragma unroll 4
      for (int c = 0; c < 16; ++c) {
        const float4 a4 = *(const float4*)&s1m[c][h1l][wg * 4];
        const float* xr = &s2m[c][h1l + j][wg * 4];
        const float4 b0 = *(const float4*)&xr[0];
        const float4 b1 = *(const float4*)&xr[4];
        const float4 b2 = *(const float4*)&xr[8];
        const float av[4]  = {a4.x, a4.y, a4.z, a4.w};
        const float xw[12] = {b0.x,b0.y,b0.z,b0.w,b1.x,b1.y,b1.z,b1.w,b2.x,b2.y,b2.z,b2.w};
        #pragma unroll
        for (int i = 0; i < 9; ++i)
          #pragma unroll
          for (int w = 0; w < 4; ++w)
            acc[i][w] = fmaf(av[w], xw[w + i], acc[i][w]);
      }
    }
  }
  if (t >= 216) return;
  const int h1 = h1base + h1l, w1 = wg * 4;
  #pragma unroll
  for (int i = 0; i < 9; ++i) {
    const int k = j * 9 + i;
    #pragma unroll
    for (int w = 0; w < 4; ++w)
      atomicAdd(&out[((size_t)(b * NK + k) * H1 + h1) * W1 + w1 + w],
                acc[i][w] * (1.f / 256.f));
  }
}

extern "C" void kernel_launch(void* const* d_in, const int* in_sizes, int n_in,
                              void* d_out, int out_size, void* d_ws, size_t ws_size,
                              hipStream_t stream) {
  const float* x1 = (const float*)d_in[0];
  const float* x2 = (const float*)d_in[1];
  float* out = (float*)d_out;

  const size_t need = (size_t)CZ * NTILE * PPT * sizeof(__half);  // ~5.97 MB
  if (ws_size >= need) {
    __half* part = (__half*)d_ws;
    corr_mfma<<<dim3(12, 16, CZ), 384, 0, stream>>>(x1, x2, part);
    corr_reduce<<<(OUTSZ / 4 + 255) / 256, 256, 0, stream>>>(part, out);
  } else {
    hipMemsetAsync(d_out, 0, (size_t)OUTSZ * sizeof(float), stream);
    corr_atomic<<<dim3(6, 16, 8), 256, 0, stream>>>(x1, x2, out);
  }
}